// Round 6
// baseline (56.811 us; speedup 1.0000x reference)
//
#include <hip/hip_runtime.h>

#define B_ 64
#define K_ 16
#define N_ 65536
#define CHUNKS 16
#define CW (N_ / CHUNKS)          // 4096 columns per block
#define KB_PER_WAVE (CW / 32 / 4) // 32 kblocks of 32 cols per wave
#define U_ 4                      // kblocks per pipeline group
#define NGRP (KB_PER_WAVE / U_)   // 8 groups
#define REC 272                   // 256 gram + 16 rowsums per BLOCK record
#define NPAIR 120
#define EPS_ 1e-8f
#define SMOOTH_ 0.1f

typedef __attribute__((ext_vector_type(8))) short bf16x8;
typedef __attribute__((ext_vector_type(4))) float f32x4;   // native vector: ok for nontemporal builtin

// ws layout (floats): [0]=counter(uint bits) [1]=sum  [16..] block records [1024*272]
#define WS_REC_OFF 16

// RNE f32 -> bf16 bit pattern (data finite positive; no NaN path needed)
__device__ __forceinline__ short f2bf(float f) {
    unsigned u = __float_as_uint(f);
    return (short)((u + 0x7FFFu + ((u >> 16) & 1u)) >> 16);
}

// ---- DPP wave-64 sum: result lands in lane 63 ----
template <int CTRL>
__device__ __forceinline__ float dpp_add_step(float x) {
    int y = __builtin_amdgcn_update_dpp(0, __float_as_int(x), CTRL, 0xf, 0xf, true);
    return x + __int_as_float(y);
}
__device__ __forceinline__ float wave_sum_lane63(float x) {
    x = dpp_add_step<0x111>(x);
    x = dpp_add_step<0x112>(x);
    x = dpp_add_step<0x114>(x);
    x = dpp_add_step<0x118>(x);
    x = dpp_add_step<0x142>(x);
    x = dpp_add_step<0x143>(x);
    return x;
}

// Gram via MFMA: lane loads 8 f32 of row (lane&15), k-group (lane>>4) within a
// 32-col kblock; mfma(frag,frag) accumulates the 16x16 A.A^T tile.
__global__ __launch_bounds__(256, 4)
void dice_accum(const float* __restrict__ am, float* __restrict__ ws) {
    const int b     = blockIdx.x >> 4;           // CHUNKS == 16
    const int chunk = blockIdx.x & (CHUNKS - 1);
    const int tid   = threadIdx.x;
    const int lane  = tid & 63;
    const int w     = tid >> 6;
    const int row   = lane & 15;
    const int lg    = lane >> 4;                 // 0..3 k-group

    if (blockIdx.x == 0 && tid == 0) {           // reset finalize state (replay-safe)
        reinterpret_cast<unsigned*>(ws)[0] = 0u;
        ws[1] = 0.f;
    }

    const f32x4* __restrict__ rp =
        reinterpret_cast<const f32x4*>(am)
        + (size_t)(b * K_ + row) * (N_ / 4)
        + chunk * (CW / 4)
        + lg * 2;

    const int rot = (b + chunk * 5 + w * 8) & (KB_PER_WAVE - 1);

    typedef __attribute__((ext_vector_type(4))) float accv;
    accv acc = {0.f, 0.f, 0.f, 0.f};
    float rs = 0.f;

    f32x4 aA[U_][2], aB[U_][2];

#define LOADG(dst, g) { _Pragma("unroll")                                     \
    for (int u = 0; u < U_; ++u) {                                            \
        const int kb = w + 4 * (((g) * U_ + u + rot) & (KB_PER_WAVE - 1));    \
        dst[u][0] = __builtin_nontemporal_load(&rp[kb * 8]);                  \
        dst[u][1] = __builtin_nontemporal_load(&rp[kb * 8 + 1]); } }

#define COMP(src) { _Pragma("unroll")                                         \
    for (int u = 0; u < U_; ++u) {                                            \
        const float f0 = src[u][0].x, f1 = src[u][0].y,                       \
                    f2 = src[u][0].z, f3 = src[u][0].w;                       \
        const float f4 = src[u][1].x, f5 = src[u][1].y,                       \
                    f6 = src[u][1].z, f7 = src[u][1].w;                       \
        rs += ((f0 + f1) + (f2 + f3)) + ((f4 + f5) + (f6 + f7));              \
        bf16x8 frag;                                                          \
        frag[0] = f2bf(f0); frag[1] = f2bf(f1);                               \
        frag[2] = f2bf(f2); frag[3] = f2bf(f3);                               \
        frag[4] = f2bf(f4); frag[5] = f2bf(f5);                               \
        frag[6] = f2bf(f6); frag[7] = f2bf(f7);                               \
        acc = __builtin_amdgcn_mfma_f32_16x16x32_bf16(frag, frag, acc, 0, 0, 0); } }

    // 2-stage software pipeline: next group's loads in flight under cvt+MFMA.
    LOADG(aA, 0)
#pragma unroll 1
    for (int g = 0; g < NGRP - 2; g += 2) {
        LOADG(aB, g + 1)
        COMP(aA)
        LOADG(aA, g + 2)
        COMP(aB)
    }
    LOADG(aB, NGRP - 1)
    COMP(aA)
    COMP(aB)
#undef LOADG
#undef COMP

    // Block-level reduce: 4 wave tiles -> one 272-float record.
    __shared__ float G_lds[4][256];
    __shared__ float RS_lds[4][64];
#pragma unroll
    for (int j = 0; j < 4; ++j)
        G_lds[w][(lg * 4 + j) * 16 + row] = acc[j];   // C/D: row=(lane>>4)*4+j, col=lane&15
    RS_lds[w][lane] = rs;
    __syncthreads();

    float* __restrict__ rec = ws + WS_REC_OFF + (size_t)blockIdx.x * REC;
    {
        float g = G_lds[0][tid] + G_lds[1][tid] + G_lds[2][tid] + G_lds[3][tid];
        rec[tid] = g;
    }
    if (tid < 16) {
        float s = 0.f;
#pragma unroll
        for (int ww = 0; ww < 4; ++ww)
#pragma unroll
            for (int g2 = 0; g2 < 4; ++g2) s += RS_lds[ww][g2 * 16 + tid];
        rec[256 + tid] = s;
    }
}

// Per-b: sum 16 block records, compute dice partial, last block writes scalar.
__global__ __launch_bounds__(256)
void dice_finalize(float* __restrict__ ws, float* __restrict__ out) {
    const int b   = blockIdx.x;
    const int tid = threadIdx.x;
    __shared__ float G[256];
    __shared__ float RS[16];
    __shared__ float red[128];
    __shared__ float bpart;

    const float* __restrict__ base = ws + WS_REC_OFF + (size_t)b * CHUNKS * REC;

    float g = 0.f;
#pragma unroll
    for (int r = 0; r < CHUNKS; ++r) g += base[r * REC + tid];
    G[tid] = g;
    if (tid < 16) {
        float s = 0.f;
#pragma unroll
        for (int r = 0; r < CHUNKS; ++r) s += base[r * REC + 256 + tid];
        RS[tid] = s;
    }
    __syncthreads();

    float acc = 0.f;
    if (tid < NPAIR) {
        int rem = tid, k = 0;
        while (rem >= K_ - 1 - k) { rem -= K_ - 1 - k; ++k; }
        const int l = k + 1 + rem;
        const float rsk = RS[k], rsl = RS[l];
        const float dk = rsk + EPS_, dl = rsl + EPS_;
        const float gram = G[k * 16 + l] / (dk * dl);   // normalized gram
        const float u    = rsk / dk + rsl / dl;         // sums_k + sums_l
        acc = (2.f * gram + SMOOTH_) / (u + SMOOTH_);
    }
    if (tid < 128) red[tid] = acc;
    __syncthreads();
    if (tid < 64) {
        float t = red[tid] + red[tid + 64];
        t = wave_sum_lane63(t);
        if (tid == 63) bpart = t;
    }
    __syncthreads();

    if (tid == 0) {
        atomicAdd(&ws[1], bpart);                 // device-scope by default
        __threadfence();
        unsigned old = atomicAdd(reinterpret_cast<unsigned*>(ws), 1u);
        if (old == B_ - 1) {                      // last block: all sums visible
            __threadfence();
            float total = __hip_atomic_load(&ws[1], __ATOMIC_RELAXED,
                                            __HIP_MEMORY_SCOPE_AGENT);
            out[0] = total / (float)(B_ * NPAIR);
        }
    }
}

extern "C" void kernel_launch(void* const* d_in, const int* in_sizes, int n_in,
                              void* d_out, int out_size, void* d_ws, size_t ws_size,
                              hipStream_t stream) {
    const float* am = (const float*)d_in[0];
    float* ws  = (float*)d_ws;
    float* out = (float*)d_out;

    hipLaunchKernelGGL(dice_accum, dim3(B_ * CHUNKS), dim3(256), 0, stream, am, ws);
    hipLaunchKernelGGL(dice_finalize, dim3(B_), dim3(256), 0, stream, ws, out);
}

// Round 7
// 49.687 us; speedup vs baseline: 1.1434x; 1.1434x over previous
//
#include <hip/hip_runtime.h>
#include <stdint.h>

#define B_ 64
#define K_ 16
#define N_ 65536
#define CHUNKS 16
#define CW (N_ / CHUNKS)            // 4096 cols per block
#define STEPS 16                    // col-blocks per chunk
#define SCOLS 256                   // cols per step
#define ROWB (SCOLS * 4)            // 1024 B staged per row per step
#define BUFB (K_ * ROWB)            // 16 KB per buffer
#define ROWSTRIDE ((size_t)N_ * 4)  // 256 KB
#define REC 272                     // 256 gram + 16 rowsums per block record
#define NPAIR 120
#define EPS_ 1e-8f
#define SMOOTH_ 0.1f

typedef __attribute__((ext_vector_type(8))) short bf16x8;
typedef __attribute__((ext_vector_type(4))) float f32x4;

// ws layout (floats): [0]=counter [1]=sum [16..] block records (1024*272)
#define WS_REC_OFF 16

typedef const __attribute__((address_space(1))) uint32_t* gas1_t;
typedef __attribute__((address_space(3))) uint32_t*       las3_t;
__device__ __forceinline__ void gload_lds16(const void* g, void* l) {
    __builtin_amdgcn_global_load_lds((gas1_t)g, (las3_t)l, 16, 0, 0);
}

// RNE f32 -> bf16 bit pattern (data finite positive)
__device__ __forceinline__ short f2bf(float f) {
    unsigned u = __float_as_uint(f);
    return (short)((u + 0x7FFFu + ((u >> 16) & 1u)) >> 16);
}

// ---- DPP wave-64 sum: result lands in lane 63 ----
template <int CTRL>
__device__ __forceinline__ float dpp_add_step(float x) {
    int y = __builtin_amdgcn_update_dpp(0, __float_as_int(x), CTRL, 0xf, 0xf, true);
    return x + __int_as_float(y);
}
__device__ __forceinline__ float wave_sum_lane63(float x) {
    x = dpp_add_step<0x111>(x);
    x = dpp_add_step<0x112>(x);
    x = dpp_add_step<0x114>(x);
    x = dpp_add_step<0x118>(x);
    x = dpp_add_step<0x142>(x);
    x = dpp_add_step<0x143>(x);
    return x;
}

// LDS-staged Gram: each staging instruction reads 1KB CONTIGUOUS from one row
// (global_load_lds, pre-swizzled source); fragments assembled via swizzled
// ds_read_b128. Double-buffered, one barrier per 256-col step.
__global__ __launch_bounds__(256, 4)
void dice_accum(const float* __restrict__ am, float* __restrict__ ws) {
    const int b     = blockIdx.x >> 4;           // CHUNKS == 16
    const int chunk = blockIdx.x & (CHUNKS - 1);
    const int tid   = threadIdx.x;
    const int lane  = tid & 63;
    const int w     = tid >> 6;
    const int row   = lane & 15;
    const int lg    = lane >> 4;                 // 0..3 k-group

    if (blockIdx.x == 0 && tid == 0) {           // reset finalize state (safe: separate dispatch uses it)
        reinterpret_cast<unsigned*>(ws)[0] = 0u;
        ws[1] = 0.f;
    }

    __shared__ __align__(16) char smem[2 * BUFB];   // 32 KB double buffer

    const char* gbase = (const char*)am
        + (size_t)(b * K_) * ROWSTRIDE + (size_t)chunk * (CW * 4);
    const int rot = (b + chunk * 5) & (STEPS - 1);  // channel-phase de-aliasing

    f32x4 acc = {0.f, 0.f, 0.f, 0.f};
    float rs = 0.f;
    const int xrd = (row >> 1) & 3;              // read-side XOR (32B units)

    // stage: wave w stages rows 4w..4w+3 of col-block (s+rot); 1KB contiguous
    // per instruction; source pre-swizzled so LDS 32B-unit u of row r sits at
    // physical unit u ^ ((r>>1)&3)  (linear dest per G21).
    auto stage = [&](int bi, int s) {
        const size_t cs = (size_t)((s + rot) & (STEPS - 1)) * ROWB;
#pragma unroll
        for (int j = 0; j < 4; ++j) {
            const int r  = w * 4 + j;
            const int xr = (r >> 1) & 3;
            const char* src = gbase + (size_t)r * ROWSTRIDE + cs
                              + (size_t)((lane * 16) ^ (xr * 32));
            gload_lds16(src, smem + bi * BUFB + r * ROWB);
        }
    };
    // compute: wave w handles kblocks {w, w+4} of the staged 256 cols.
    auto compute = [&](int bi) {
#pragma unroll
        for (int t = 0; t < 2; ++t) {
            const int kb = w + 4 * t;
            const int p  = (kb * 4 + lg) ^ xrd;  // swizzled 32B unit
            const f32x4* q = (const f32x4*)(smem + bi * BUFB + row * ROWB + p * 32);
            const f32x4 d0 = q[0];
            const f32x4 d1 = q[1];
            rs += ((d0.x + d0.y) + (d0.z + d0.w)) + ((d1.x + d1.y) + (d1.z + d1.w));
            bf16x8 frag;
            frag[0] = f2bf(d0.x); frag[1] = f2bf(d0.y);
            frag[2] = f2bf(d0.z); frag[3] = f2bf(d0.w);
            frag[4] = f2bf(d1.x); frag[5] = f2bf(d1.y);
            frag[6] = f2bf(d1.z); frag[7] = f2bf(d1.w);
            acc = __builtin_amdgcn_mfma_f32_16x16x32_bf16(frag, frag, acc, 0, 0, 0);
        }
    };

    stage(0, 0);
    __syncthreads();                              // drains vmcnt (compiler) + barrier
#pragma unroll 1
    for (int s = 1; s < STEPS; ++s) {
        stage(s & 1, s);                          // issue next-step loads first
        compute((s - 1) & 1);                     // compute current under load latency
        __syncthreads();
    }
    compute((STEPS - 1) & 1);

    // Block-level reduce into one 272-float record (reuse buf0 region; no wave
    // reads buf0 after the last in-loop barrier).
    float* G_lds  = (float*)smem;                 // [4][256]
    float* RS_lds = (float*)(smem + 4096);        // [4][64]
#pragma unroll
    for (int j = 0; j < 4; ++j)
        G_lds[w * 256 + (lg * 4 + j) * 16 + row] = acc[j];  // C/D: row=(lane>>4)*4+j, col=lane&15
    RS_lds[w * 64 + lane] = rs;
    __syncthreads();

    float* __restrict__ rec = ws + WS_REC_OFF + (size_t)blockIdx.x * REC;
    {
        float g = G_lds[0 * 256 + tid] + G_lds[1 * 256 + tid]
                + G_lds[2 * 256 + tid] + G_lds[3 * 256 + tid];
        rec[tid] = g;
    }
    if (tid < 16) {
        float s = 0.f;
#pragma unroll
        for (int ww = 0; ww < 4; ++ww)
#pragma unroll
            for (int g2 = 0; g2 < 4; ++g2) s += RS_lds[ww * 64 + g2 * 16 + tid];
        rec[256 + tid] = s;
    }
}

// Per-b: sum 16 block records, compute dice partial, last block writes scalar.
__global__ __launch_bounds__(256)
void dice_finalize(float* __restrict__ ws, float* __restrict__ out) {
    const int b   = blockIdx.x;
    const int tid = threadIdx.x;
    __shared__ float G[256];
    __shared__ float RS[16];
    __shared__ float red[128];
    __shared__ float bpart;

    const float* __restrict__ base = ws + WS_REC_OFF + (size_t)b * CHUNKS * REC;

    float g = 0.f;
#pragma unroll
    for (int r = 0; r < CHUNKS; ++r) g += base[r * REC + tid];
    G[tid] = g;
    if (tid < 16) {
        float s = 0.f;
#pragma unroll
        for (int r = 0; r < CHUNKS; ++r) s += base[r * REC + 256 + tid];
        RS[tid] = s;
    }
    __syncthreads();

    float acc = 0.f;
    if (tid < NPAIR) {
        int rem = tid, k = 0;
        while (rem >= K_ - 1 - k) { rem -= K_ - 1 - k; ++k; }
        const int l = k + 1 + rem;
        const float rsk = RS[k], rsl = RS[l];
        const float dk = rsk + EPS_, dl = rsl + EPS_;
        const float gram = G[k * 16 + l] / (dk * dl);   // normalized gram
        const float u    = rsk / dk + rsl / dl;         // sums_k + sums_l
        acc = (2.f * gram + SMOOTH_) / (u + SMOOTH_);
    }
    if (tid < 128) red[tid] = acc;
    __syncthreads();
    if (tid < 64) {
        float t = red[tid] + red[tid + 64];
        t = wave_sum_lane63(t);
        if (tid == 63) bpart = t;
    }
    __syncthreads();

    if (tid == 0) {
        atomicAdd(&ws[1], bpart);                 // device-scope by default
        __threadfence();
        unsigned old = atomicAdd(reinterpret_cast<unsigned*>(ws), 1u);
        if (old == B_ - 1) {                      // last block: all sums visible
            __threadfence();
            float total = __hip_atomic_load(&ws[1], __ATOMIC_RELAXED,
                                            __HIP_MEMORY_SCOPE_AGENT);
            out[0] = total / (float)(B_ * NPAIR);
        }
    }
}

extern "C" void kernel_launch(void* const* d_in, const int* in_sizes, int n_in,
                              void* d_out, int out_size, void* d_ws, size_t ws_size,
                              hipStream_t stream) {
    const float* am = (const float*)d_in[0];
    float* ws  = (float*)d_ws;
    float* out = (float*)d_out;

    hipLaunchKernelGGL(dice_accum, dim3(B_ * CHUNKS), dim3(256), 0, stream, am, ws);
    hipLaunchKernelGGL(dice_finalize, dim3(B_), dim3(256), 0, stream, ws, out);
}

// Round 8
// 49.349 us; speedup vs baseline: 1.1512x; 1.0068x over previous
//
#include <hip/hip_runtime.h>
#include <stdint.h>

#define B_ 64
#define K_ 16
#define N_ 65536
#define CHUNKS 16
#define CW (N_ / CHUNKS)            // 4096 cols per block
#define STEPS 16                    // col-blocks per chunk
#define SCOLS 256                   // cols per step
#define ROWB (SCOLS * 4)            // 1024 B staged per row per step
#define BUFB (K_ * ROWB)            // 16 KB per buffer
#define NBUF 3                      // 3-deep pipeline
#define ROWSTRIDE ((size_t)N_ * 4)  // 256 KB
#define REC 272                     // 256 gram + 16 rowsums per block record
#define NPAIR 120
#define EPS_ 1e-8f
#define SMOOTH_ 0.1f

typedef __attribute__((ext_vector_type(8))) short bf16x8;
typedef __attribute__((ext_vector_type(4))) float f32x4;

// ws layout (floats): [0]=counter [1]=sum [16..] block records (1024*272)
#define WS_REC_OFF 16

typedef const __attribute__((address_space(1))) uint32_t* gas1_t;
typedef __attribute__((address_space(3))) uint32_t*       las3_t;
__device__ __forceinline__ void gload_lds16(const void* g, void* l) {
    __builtin_amdgcn_global_load_lds((gas1_t)g, (las3_t)l, 16, 0, 0);
}

#define VMCNT(n) do { asm volatile("s_waitcnt vmcnt(" #n ")" ::: "memory"); \
                      __builtin_amdgcn_sched_barrier(0); } while (0)
#define BARRIER() asm volatile("s_barrier" ::: "memory")

// RNE f32 -> bf16 bit pattern (data finite positive)
__device__ __forceinline__ short f2bf(float f) {
    unsigned u = __float_as_uint(f);
    return (short)((u + 0x7FFFu + ((u >> 16) & 1u)) >> 16);
}

// ---- DPP wave-64 sum: result lands in lane 63 ----
template <int CTRL>
__device__ __forceinline__ float dpp_add_step(float x) {
    int y = __builtin_amdgcn_update_dpp(0, __float_as_int(x), CTRL, 0xf, 0xf, true);
    return x + __int_as_float(y);
}
__device__ __forceinline__ float wave_sum_lane63(float x) {
    x = dpp_add_step<0x111>(x);
    x = dpp_add_step<0x112>(x);
    x = dpp_add_step<0x114>(x);
    x = dpp_add_step<0x118>(x);
    x = dpp_add_step<0x142>(x);
    x = dpp_add_step<0x143>(x);
    return x;
}

// LDS-staged Gram, 3-deep counted-vmcnt pipeline:
// per step: vmcnt(4) [own stage(s) done, BEFORE barrier => cross-wave safe]
//           -> s_barrier -> stage(s+2) -> compute(s).
// stage(s+1)/(s+2) stay in flight across barriers (never drain to 0 mid-loop).
__global__ __launch_bounds__(256, 3)
void dice_accum(const float* __restrict__ am, float* __restrict__ ws) {
    const int b     = blockIdx.x >> 4;           // CHUNKS == 16
    const int chunk = blockIdx.x & (CHUNKS - 1);
    const int tid   = threadIdx.x;
    const int lane  = tid & 63;
    const int w     = tid >> 6;
    const int row   = lane & 15;
    const int lg    = lane >> 4;                 // 0..3 k-group

    if (blockIdx.x == 0 && tid == 0) {           // reset finalize state
        reinterpret_cast<unsigned*>(ws)[0] = 0u;
        ws[1] = 0.f;
    }

    __shared__ __align__(16) char smem[NBUF * BUFB];   // 48 KB triple buffer

    const char* gbase = (const char*)am
        + (size_t)(b * K_) * ROWSTRIDE + (size_t)chunk * (CW * 4);
    const int rot = (b + chunk * 5) & (STEPS - 1);  // channel-phase de-aliasing

    f32x4 acc = {0.f, 0.f, 0.f, 0.f};
    float rs = 0.f;
    const int xrd = (row >> 1) & 3;              // read-side XOR (32B units)

    // wave w stages rows 4w..4w+3; 1KB contiguous global read per instruction;
    // source pre-swizzled so LDS 32B-unit u of row r sits at u ^ ((r>>1)&3).
    auto stage = [&](int bi, int s) {
        const size_t cs = (size_t)((s + rot) & (STEPS - 1)) * ROWB;
#pragma unroll
        for (int j = 0; j < 4; ++j) {
            const int r  = w * 4 + j;
            const int xr = (r >> 1) & 3;
            const char* src = gbase + (size_t)r * ROWSTRIDE + cs
                              + (size_t)((lane * 16) ^ (xr * 32));
            gload_lds16(src, smem + bi * BUFB + r * ROWB);
        }
    };
    // wave w computes kblocks {w, w+4} of the staged 256 cols.
    auto compute = [&](int bi) {
#pragma unroll
        for (int t = 0; t < 2; ++t) {
            const int kb = w + 4 * t;
            const int p  = (kb * 4 + lg) ^ xrd;  // swizzled 32B unit
            const f32x4* q = (const f32x4*)(smem + bi * BUFB + row * ROWB + p * 32);
            const f32x4 d0 = q[0];
            const f32x4 d1 = q[1];
            rs += ((d0.x + d0.y) + (d0.z + d0.w)) + ((d1.x + d1.y) + (d1.z + d1.w));
            bf16x8 frag;
            frag[0] = f2bf(d0.x); frag[1] = f2bf(d0.y);
            frag[2] = f2bf(d0.z); frag[3] = f2bf(d0.w);
            frag[4] = f2bf(d1.x); frag[5] = f2bf(d1.y);
            frag[6] = f2bf(d1.z); frag[7] = f2bf(d1.w);
            acc = __builtin_amdgcn_mfma_f32_16x16x32_bf16(frag, frag, acc, 0, 0, 0);
        }
    };

    stage(0, 0);
    stage(1, 1);
    int bs = 2, bc = 0;
#pragma unroll 1
    for (int s = 0; s < STEPS - 1; ++s) {        // s = 0..14
        VMCNT(4);                                // own stage(s) complete (pre-barrier!)
        BARRIER();                               // => ALL waves' stage(s) complete
        if (s < STEPS - 2) {                     // stage(s+2); WAR safe post-barrier
            stage(bs, s + 2);
            bs = (bs == 2) ? 0 : bs + 1;
        }
        compute(bc);
        bc = (bc == 2) ? 0 : bc + 1;
    }
    VMCNT(0);                                    // last buffer (stage(15)) complete
    BARRIER();
    compute(bc);                                 // s = 15

    __syncthreads();                             // all staging reads done
    // Block-level reduce into one 272-float record (reuse staging LDS).
    float* G_lds  = (float*)smem;                // [4][256]
    float* RS_lds = (float*)(smem + 4096);       // [4][64]
#pragma unroll
    for (int j = 0; j < 4; ++j)
        G_lds[w * 256 + (lg * 4 + j) * 16 + row] = acc[j];  // C/D: row=(lane>>4)*4+j, col=lane&15
    RS_lds[w * 64 + lane] = rs;
    __syncthreads();

    float* __restrict__ rec = ws + WS_REC_OFF + (size_t)blockIdx.x * REC;
    {
        float g = G_lds[0 * 256 + tid] + G_lds[1 * 256 + tid]
                + G_lds[2 * 256 + tid] + G_lds[3 * 256 + tid];
        rec[tid] = g;
    }
    if (tid < 16) {
        float s = 0.f;
#pragma unroll
        for (int ww = 0; ww < 4; ++ww)
#pragma unroll
            for (int g2 = 0; g2 < 4; ++g2) s += RS_lds[ww * 64 + g2 * 16 + tid];
        rec[256 + tid] = s;
    }
}

// Per-b: sum 16 block records, compute dice partial, last block writes scalar.
__global__ __launch_bounds__(256)
void dice_finalize(float* __restrict__ ws, float* __restrict__ out) {
    const int b   = blockIdx.x;
    const int tid = threadIdx.x;
    __shared__ float G[256];
    __shared__ float RS[16];
    __shared__ float red[128];
    __shared__ float bpart;

    const float* __restrict__ base = ws + WS_REC_OFF + (size_t)b * CHUNKS * REC;

    float g = 0.f;
#pragma unroll
    for (int r = 0; r < CHUNKS; ++r) g += base[r * REC + tid];
    G[tid] = g;
    if (tid < 16) {
        float s = 0.f;
#pragma unroll
        for (int r = 0; r < CHUNKS; ++r) s += base[r * REC + 256 + tid];
        RS[tid] = s;
    }
    __syncthreads();

    float acc = 0.f;
    if (tid < NPAIR) {
        int rem = tid, k = 0;
        while (rem >= K_ - 1 - k) { rem -= K_ - 1 - k; ++k; }
        const int l = k + 1 + rem;
        const float rsk = RS[k], rsl = RS[l];
        const float dk = rsk + EPS_, dl = rsl + EPS_;
        const float gram = G[k * 16 + l] / (dk * dl);   // normalized gram
        const float u    = rsk / dk + rsl / dl;         // sums_k + sums_l
        acc = (2.f * gram + SMOOTH_) / (u + SMOOTH_);
    }
    if (tid < 128) red[tid] = acc;
    __syncthreads();
    if (tid < 64) {
        float t = red[tid] + red[tid + 64];
        t = wave_sum_lane63(t);
        if (tid == 63) bpart = t;
    }
    __syncthreads();

    if (tid == 0) {
        atomicAdd(&ws[1], bpart);                 // device-scope by default
        __threadfence();
        unsigned old = atomicAdd(reinterpret_cast<unsigned*>(ws), 1u);
        if (old == B_ - 1) {                      // last block: all sums visible
            __threadfence();
            float total = __hip_atomic_load(&ws[1], __ATOMIC_RELAXED,
                                            __HIP_MEMORY_SCOPE_AGENT);
            out[0] = total / (float)(B_ * NPAIR);
        }
    }
}

extern "C" void kernel_launch(void* const* d_in, const int* in_sizes, int n_in,
                              void* d_out, int out_size, void* d_ws, size_t ws_size,
                              hipStream_t stream) {
    const float* am = (const float*)d_in[0];
    float* ws  = (float*)d_ws;
    float* out = (float*)d_out;

    hipLaunchKernelGGL(dice_accum, dim3(B_ * CHUNKS), dim3(256), 0, stream, am, ws);
    hipLaunchKernelGGL(dice_finalize, dim3(B_), dim3(256), 0, stream, ws, out);
}